// Round 22
// baseline (559.618 us; speedup 1.0000x reference)
//
#include <hip/hip_runtime.h>
#include <math.h>

#define T_TOK 8192
#define DDIM  1024
#define HDIM  4096
#define NEXP  8
#define BM    128                     /* row tile */
#define BN    128                     /* col tile */
#define BK    64                      /* shorts per K-tile */
#define MAXROWS (T_TOK*2 + NEXP*BM)   /* 17408 */
#define MAXTILES (MAXROWS/BM)         /* 136 */
#define KS2   2                       /* split-K for legacy atomic ffn2 */
#define NGATE (T_TOK/8)               /* 1024 gate blocks */
#define NTR1  ((HDIM/64)*(DDIM/64)*NEXP)   /* 8192 */
#define NTR2  ((DDIM/64)*(HDIM/64)*NEXP)   /* 8192 */

typedef __attribute__((ext_vector_type(8))) short short8;
typedef __attribute__((ext_vector_type(4))) short short4v;
typedef __attribute__((ext_vector_type(4))) float f32x4;

typedef const __attribute__((address_space(1))) unsigned int* gp1_t;
typedef __attribute__((address_space(3))) unsigned int* lp3_t;

__device__ __forceinline__ void gld16(const void* g, void* l) {
  __builtin_amdgcn_global_load_lds((gp1_t)g, (lp3_t)l, 16, 0, 0);
}

__device__ __forceinline__ short f2bf(float f) {
  unsigned u = __float_as_uint(f);
  u += 0x7fffu + ((u >> 16) & 1u);   // RNE
  return (short)(u >> 16);
}

__device__ __forceinline__ float bf2f(short s) {
  return __uint_as_float(((unsigned)(unsigned short)s) << 16);
}

// A&S 7.1.25 erf approximation, |eps| <= 5e-4 (<< bf16 ulp of h); NO transcendental
__device__ __forceinline__ float erf_fast(float x) {
  float ax = fabsf(x);
  float t = 1.f + ax * (0.278393f + ax * (0.230389f + ax * (0.000972f + ax * 0.078108f)));
  float t2 = t * t;
  float r = 1.f - __builtin_amdgcn_rcpf(t2 * t2);
  return copysignf(r, x);
}

// ---- transpose body: wt[e][c][r] = bf16(w[e][r][c]), one 64x64 tile ----
__device__ __forceinline__ void tr_body(float* sl /*[64][65]*/,
    const float* __restrict__ w, short* __restrict__ wt, int R, int C, int lb) {
  int ctiles = C / 64, rtiles = R / 64;
  int e  = lb / (ctiles * rtiles);
  int rm = lb % (ctiles * rtiles);
  int r0 = (rm / ctiles) * 64;
  int c0 = (rm % ctiles) * 64;
  const float* W = w + (size_t)e * R * C;
  short* O = wt + (size_t)e * R * C;
  int t = threadIdx.x;
  int lr = t >> 4, lc4 = (t & 15) * 4;
#pragma unroll
  for (int i = 0; i < 4; i++) {
    float4 v = *(const float4*)&W[(size_t)(r0 + lr + i * 16) * C + c0 + lc4];
    sl[(lr + i * 16) * 65 + lc4 + 0] = v.x;
    sl[(lr + i * 16) * 65 + lc4 + 1] = v.y;
    sl[(lr + i * 16) * 65 + lc4 + 2] = v.z;
    sl[(lr + i * 16) * 65 + lc4 + 3] = v.w;
  }
  __syncthreads();
#pragma unroll
  for (int i = 0; i < 4; i++) {
    int oc = lr + i * 16;
    short4v s;
#pragma unroll
    for (int j = 0; j < 4; j++) s[j] = f2bf(sl[(lc4 + j) * 65 + oc]);
    *(short4v*)&O[(size_t)(c0 + oc) * R + r0 + lc4] = s;
  }
}

// ---- gate body: logits, top-2, fused xb; NO global atomics (bcnt histogram) ----
__device__ __forceinline__ void gate_body(char* smem, int bid,
    const float* __restrict__ x, const float* __restrict__ gw,
    const float* __restrict__ gb, int2* __restrict__ toke,
    float2* __restrict__ tokw, int* __restrict__ bcnt, short* __restrict__ xb) {
  float* sg = (float*)smem;                   // [e][d], 32 KB
  int* lcnt = (int*)(smem + NEXP * DDIM * 4); // 8 ints
  int t = threadIdx.x;
#pragma unroll
  for (int it = 0; it < 8; ++it) {
    int l0 = (it * 256 + t) * 4;               // linear gw index (d*8+e)
    float4 v = *(const float4*)&gw[l0];
    int d = l0 >> 3, e0 = l0 & 7;
    sg[(e0 + 0) * DDIM + d] = v.x;
    sg[(e0 + 1) * DDIM + d] = v.y;
    sg[(e0 + 2) * DDIM + d] = v.z;
    sg[(e0 + 3) * DDIM + d] = v.w;
  }
  if (t < NEXP) lcnt[t] = 0;
  __syncthreads();
  int wave = t >> 6, lane = t & 63;
  int tok0 = bid * 8 + wave * 2;
#pragma unroll
  for (int tk = 0; tk < 2; ++tk) {
    int tok = tok0 + tk;
    float p[NEXP];
#pragma unroll
    for (int e = 0; e < NEXP; e++) p[e] = 0.f;
#pragma unroll
    for (int c = 0; c < 4; c++) {
      int d = c * 256 + lane * 4;
      float4 xv = *(const float4*)&x[(size_t)tok * DDIM + d];
      short4v sv;
      sv[0] = f2bf(xv.x); sv[1] = f2bf(xv.y); sv[2] = f2bf(xv.z); sv[3] = f2bf(xv.w);
      *(short4v*)&xb[(size_t)tok * DDIM + d] = sv;
#pragma unroll
      for (int e = 0; e < NEXP; e++) {
        float4 g = *(const float4*)&sg[e * DDIM + d];
        p[e] += xv.x * g.x + xv.y * g.y + xv.z * g.z + xv.w * g.w;
      }
    }
#pragma unroll
    for (int off = 32; off; off >>= 1)
#pragma unroll
      for (int e = 0; e < NEXP; e++) p[e] += __shfl_xor(p[e], off);
    if (lane == 0) {
      float l[NEXP];
#pragma unroll
      for (int e = 0; e < NEXP; e++) l[e] = p[e] + gb[e];
      int i0 = 0;
#pragma unroll
      for (int e = 1; e < NEXP; e++) if (l[e] > l[i0]) i0 = e;   // first-max (jax tie-break)
      int i1 = (i0 == 0) ? 1 : 0;
#pragma unroll
      for (int e = 0; e < NEXP; e++) if (e != i0 && l[e] > l[i1]) i1 = e;
      float ex = expf(l[i1] - l[i0]);
      float w0 = 1.f / (1.f + ex);
      toke[tok] = make_int2(i0, i1);
      tokw[tok] = make_float2(w0, 1.f - w0);
      atomicAdd(&lcnt[i0], 1);   // LDS-scope
      atomicAdd(&lcnt[i1], 1);
    }
  }
  __syncthreads();
  if (t < NEXP) bcnt[bid * NEXP + t] = lcnt[t];
}

// ---- fused front kernel: gate blocks + w1-transpose blocks + w2-transpose blocks ----
__global__ __launch_bounds__(256) void k_front(const float* __restrict__ x,
    const float* __restrict__ gw, const float* __restrict__ gb,
    const float* __restrict__ w1, const float* __restrict__ w2,
    int2* __restrict__ toke, float2* __restrict__ tokw, int* __restrict__ bcnt,
    short* __restrict__ xb, short* __restrict__ w1t, short* __restrict__ w2t) {
  __shared__ char smem[NEXP * DDIM * 4 + 64];
  int bid = blockIdx.x;
  if (bid < NGATE) {
    gate_body(smem, bid, x, gw, gb, toke, tokw, bcnt, xb);
  } else if (bid < NGATE + NTR1) {
    tr_body((float*)smem, w1, w1t, DDIM, HDIM, bid - NGATE);
  } else {
    tr_body((float*)smem, w2, w2t, HDIM, DDIM, bid - NGATE - NTR1);
  }
}

// ---------------- routing plan (256 threads; sums bcnt) ----------------
__global__ __launch_bounds__(256) void k_plan(const int* __restrict__ bcnt,
    int* __restrict__ pbase, int* __restrict__ texp) {
  __shared__ int tot[NEXP];
  __shared__ int b[NEXP + 1];
  int t = threadIdx.x;
  if (t < NEXP) tot[t] = 0;
  __syncthreads();
  int e = t & 7, sum = 0;
  for (int i = t >> 3; i < NGATE; i += 32) sum += bcnt[i * NEXP + e];
  atomicAdd(&tot[e], sum);
  __syncthreads();
  if (t == 0) {
    b[0] = 0;
#pragma unroll
    for (int ee = 0; ee < NEXP; ee++)
      b[ee + 1] = b[ee] + ((tot[ee] + BM - 1) & ~(BM - 1));
#pragma unroll
    for (int ee = 0; ee < NEXP; ee++) pbase[ee] = b[ee];
  }
  __syncthreads();
  for (int i = t; i < MAXTILES; i += 256) {
    int r0 = i * BM, ee = -1;
#pragma unroll
    for (int k = 0; k < NEXP; k++) if (r0 >= b[k] && r0 < b[k + 1]) ee = k;
    texp[i] = ee;
  }
}

// scatter: also records tok -> (row0,row1) for the atomic-free combine
__global__ __launch_bounds__(256) void k_scatter(const int2* __restrict__ toke,
    const float2* __restrict__ tokw, const int* __restrict__ pbase,
    int* __restrict__ fill, int* __restrict__ rtok, float* __restrict__ rwgt,
    int* __restrict__ trow) {
  int tok = blockIdx.x * 256 + threadIdx.x;
  if (tok >= T_TOK) return;
  int2 te = toke[tok];
  float2 tw = tokw[tok];
  int s0 = atomicAdd(&fill[te.x], 1);
  int r0 = pbase[te.x] + s0;
  rtok[r0] = tok; rwgt[r0] = tw.x; trow[tok * 2] = r0;
  int s1 = atomicAdd(&fill[te.y], 1);
  int r1 = pbase[te.y] + s1;
  rtok[r1] = tok; rwgt[r1] = tw.y; trow[tok * 2 + 1] = r1;
}

// ---- combine: out[tok] = w0*(row0+b2[e0]) + w1*(row1+b2[e1]); bf16 out2 ----
__global__ __launch_bounds__(256) void k_out(const short* __restrict__ out2b,
    const float* __restrict__ b2, const int2* __restrict__ toke,
    const float2* __restrict__ tokw, const int* __restrict__ trow,
    float* __restrict__ out) {
  int idx = blockIdx.x * 256 + threadIdx.x;
  int tok = idx >> 8;                 // 256 float4 per 1024-dim row
  int seg = (idx & 255) * 4;
  int2 te = toke[tok];
  float2 tw = tokw[tok];
  int r0 = trow[tok * 2], r1 = trow[tok * 2 + 1];
  short4v a4 = *(const short4v*)&out2b[(size_t)r0 * DDIM + seg];
  short4v c4 = *(const short4v*)&out2b[(size_t)r1 * DDIM + seg];
  float4 p0 = *(const float4*)&b2[te.x * DDIM + seg];
  float4 p1 = *(const float4*)&b2[te.y * DDIM + seg];
  float4 o;
  o.x = tw.x * (bf2f(a4[0]) + p0.x) + tw.y * (bf2f(c4[0]) + p1.x);
  o.y = tw.x * (bf2f(a4[1]) + p0.y) + tw.y * (bf2f(c4[1]) + p1.y);
  o.z = tw.x * (bf2f(a4[2]) + p0.z) + tw.y * (bf2f(c4[2]) + p1.z);
  o.w = tw.x * (bf2f(a4[3]) + p0.w) + tw.y * (bf2f(c4[3]) + p1.w);
  *(float4*)&out[(size_t)tok * DDIM + seg] = o;
}

// ============== 128x128-tile grouped GEMM, 4 waves (2M x 2N, 64x64/wave) ==========
// Round-13/16 proven config: 4 blocks/CU, XOR-8 swizzle (0 conflicts).

#define STG(ko) { \
  gld16(sA[0] + (ko), &AL[(0 * 32 + wid * 8) * BK]); \
  gld16(sA[1] + (ko), &AL[(1 * 32 + wid * 8) * BK]); \
  gld16(sA[2] + (ko), &AL[(2 * 32 + wid * 8) * BK]); \
  gld16(sA[3] + (ko), &AL[(3 * 32 + wid * 8) * BK]); \
  gld16(sB[0] + (ko), &BL[(0 * 32 + wid * 8) * BK]); \
  gld16(sB[1] + (ko), &BL[(1 * 32 + wid * 8) * BK]); \
  gld16(sB[2] + (ko), &BL[(2 * 32 + wid * 8) * BK]); \
  gld16(sB[3] + (ko), &BL[(3 * 32 + wid * 8) * BK]); }

#define MFMA_TILE { \
  __builtin_amdgcn_s_setprio(1); \
  _Pragma("unroll") \
  for (int s = 0; s < 2; ++s) { \
    int xo = ((s * 4 + kg) ^ x7) << 3; \
    short8 af[4], bg[4]; \
    _Pragma("unroll") \
    for (int i = 0; i < 4; i++) af[i] = *(short8*)&AL[(wm + i * 16 + lr) * BK + xo]; \
    _Pragma("unroll") \
    for (int j = 0; j < 4; j++) bg[j] = *(short8*)&BL[(wn + j * 16 + lr) * BK + xo]; \
    _Pragma("unroll") \
    for (int i = 0; i < 4; i++) \
    _Pragma("unroll") \
    for (int j = 0; j < 4; j++) \
      acc[i][j] = __builtin_amdgcn_mfma_f32_16x16x32_bf16(af[i], bg[j], acc[i][j], 0, 0, 0); \
  } \
  __builtin_amdgcn_s_setprio(0); }

#define GEMM_LOOP(NKv) \
  _Pragma("unroll 4") \
  for (int kt = 0; kt < (NKv); ++kt) { \
    STG(kt * BK); \
    asm volatile("s_waitcnt vmcnt(0)" ::: "memory"); \
    __syncthreads(); \
    MFMA_TILE; \
    __syncthreads(); \
  }

// ---------------- stage 1: h = gelu(x @ w1[e] + b1[e]) ----------------
__global__ __launch_bounds__(256, 4) void k_ffn1(const short* __restrict__ xb,
    const short* __restrict__ w1t, const float* __restrict__ b1,
    const int* __restrict__ rtok, const int* __restrict__ texp,
    int tile_base, short* __restrict__ hbuf) {
  int tl = blockIdx.y;
  int tm = tile_base + tl;
  int e = texp[tm];
  if (e < 0) return;
  int n0 = blockIdx.x * BN;
  const short* W = w1t + (size_t)e * HDIM * DDIM;
  __shared__ short LDSBUF[2 * BM * BK];
  short* AL = LDSBUF;
  short* BL = LDSBUF + BM * BK;
  int t = threadIdx.x, wid = t >> 6, lane = t & 63;
  int sr8 = lane >> 3, slot = lane & 7;
  int swz = (slot ^ sr8) * 8;
  const short* sA[4]; const short* sB[4];
#pragma unroll
  for (int i = 0; i < 4; i++) {
    int r = i * 32 + wid * 8 + sr8;
    int tok = rtok[tm * BM + r]; if (tok < 0) tok = 0;
    sA[i] = xb + (size_t)tok * DDIM + swz;
    sB[i] = W + (size_t)(n0 + r) * DDIM + swz;
  }

  f32x4 acc[4][4];
#pragma unroll
  for (int i = 0; i < 4; i++)
#pragma unroll
    for (int j = 0; j < 4; j++) acc[i][j] = (f32x4){0.f, 0.f, 0.f, 0.f};

  int wm = (wid >> 1) * 64, wn = (wid & 1) * 64;
  int lr = lane & 15, kg = lane >> 4, x7 = lr & 7;

  GEMM_LOOP(DDIM / BK)   // 16

  // LDS-staged vectorized epilogue (wave-private [32][68] region, no barriers)
  short* SB = LDSBUF + wid * (32 * 68);
#pragma unroll
  for (int p = 0; p < 2; ++p) {
#pragma unroll
    for (int i2 = 0; i2 < 2; ++i2) {
      int i = p * 2 + i2;
#pragma unroll
      for (int j = 0; j < 4; ++j) {
        int col = j * 16 + lr;
        float bias = b1[e * HDIM + n0 + wn + col];
#pragma unroll
        for (int r = 0; r < 4; ++r) {
          float v = acc[i][j][r] + bias;
          v = 0.5f * v * (1.f + erf_fast(v * 0.70710678118f));
          SB[(i2 * 16 + kg * 4 + r) * 68 + col] = f2bf(v);
        }
      }
    }
    int lrow = lane >> 1, c0 = (lane & 1) * 32;
    size_t grow = (size_t)(tl * BM + wm + p * 32 + lrow);
#pragma unroll
    for (int s = 0; s < 4; ++s) {
      short8 v = *(short8*)&SB[lrow * 68 + c0 + s * 8];
      *(short8*)&hbuf[grow * HDIM + n0 + wn + c0 + s * 8] = v;
    }
  }
}

// ------- stage 2 (dense): out2b[row] = bf16(h @ w2[e]); 8x8 SUPERTILE remap -------
// flat block id -> supertile of 8 tm x 8 n0: both operands' reuse distance <= 64
// blocks (16 MB window) -> w2t panels stay LLC/L2-hot between uses.
__global__ __launch_bounds__(256, 4) void k_ffn2d(const short* __restrict__ hbuf,
    const short* __restrict__ w2t, const int* __restrict__ texp,
    int tile_base, short* __restrict__ out2b) {
  int flat = blockIdx.y * gridDim.x + blockIdx.x;
  int st = flat >> 6, wi = flat & 63;
  int tm = tile_base + st * 8 + (wi >> 3);
  int n0 = (wi & 7) * BN;
  int e = texp[tm];
  if (e < 0) return;
  const short* W = w2t + (size_t)e * DDIM * HDIM;
  __shared__ short LDSBUF[2 * BM * BK];
  short* AL = LDSBUF;
  short* BL = LDSBUF + BM * BK;
  int t = threadIdx.x, wid = t >> 6, lane = t & 63;
  int sr8 = lane >> 3, slot = lane & 7;
  int swz = (slot ^ sr8) * 8;
  const short* sA[4]; const short* sB[4];
#pragma unroll
  for (int i = 0; i < 4; i++) {
    int r = i * 32 + wid * 8 + sr8;
    sA[i] = hbuf + (size_t)(tm * BM + r) * HDIM + swz;
    sB[i] = W + (size_t)(n0 + r) * HDIM + swz;
  }

  f32x4 acc[4][4];
#pragma unroll
  for (int i = 0; i < 4; i++)
#pragma unroll
    for (int j = 0; j < 4; j++) acc[i][j] = (f32x4){0.f, 0.f, 0.f, 0.f};

  int wm = (wid >> 1) * 64, wn = (wid & 1) * 64;
  int lr = lane & 15, kg = lane >> 4, x7 = lr & 7;

  GEMM_LOOP(HDIM / BK)   // 64

  // bf16 epilogue: wave-private [16][68]-short LDS staging, short8 stores
  short* SB = LDSBUF + wid * (16 * 68);
#pragma unroll
  for (int i = 0; i < 4; ++i) {
#pragma unroll
    for (int j = 0; j < 4; ++j)
#pragma unroll
      for (int r = 0; r < 4; ++r)
        SB[(kg * 4 + r) * 68 + j * 16 + lr] = f2bf(acc[i][j][r]);
    int lrow = lane >> 2, c0 = (lane & 3) * 16;
    size_t grow = (size_t)(tm * BM + wm + i * 16 + lrow);
#pragma unroll
    for (int s = 0; s < 2; ++s) {
      short8 v = *(short8*)&SB[lrow * 68 + c0 + s * 8];
      *(short8*)&out2b[grow * DDIM + n0 + wn + c0 + s * 8] = v;
    }
  }
}

// ------- stage 2 (legacy atomic, split-K): fallback when ws is small -------
__global__ __launch_bounds__(256, 4) void k_ffn2a(const short* __restrict__ hbuf,
    const short* __restrict__ w2t, const float* __restrict__ b2,
    const int* __restrict__ rtok, const float* __restrict__ rwgt,
    const int* __restrict__ texp, int tile_base, float* __restrict__ out) {
  int tl = blockIdx.z;
  int tm = tile_base + tl;
  int e = texp[tm];
  if (e < 0) return;
  int kc = blockIdx.y;
  int n0 = blockIdx.x * BN;
  const short* W = w2t + (size_t)e * DDIM * HDIM;
  __shared__ short LDSBUF[2 * BM * BK];
  short* AL = LDSBUF;
  short* BL = LDSBUF + BM * BK;
  int t = threadIdx.x, wid = t >> 6, lane = t & 63;
  int sr8 = lane >> 3, slot = lane & 7;
  int swz = (slot ^ sr8) * 8;
  const int NK = HDIM / BK / KS2;
  int kbase = kc * NK * BK;
  const short* sA[4]; const short* sB[4];
#pragma unroll
  for (int i = 0; i < 4; i++) {
    int r = i * 32 + wid * 8 + sr8;
    sA[i] = hbuf + (size_t)(tl * BM + r) * HDIM + kbase + swz;
    sB[i] = W + (size_t)(n0 + r) * HDIM + kbase + swz;
  }
  f32x4 acc[4][4];
#pragma unroll
  for (int i = 0; i < 4; i++)
#pragma unroll
    for (int j = 0; j < 4; j++) acc[i][j] = (f32x4){0.f, 0.f, 0.f, 0.f};
  int wm = (wid >> 1) * 64, wn = (wid & 1) * 64;
  int lr = lane & 15, kg = lane >> 4, x7 = lr & 7;

  GEMM_LOOP(NK)

#pragma unroll
  for (int j = 0; j < 4; j++) {
    int gcol = n0 + wn + j * 16 + lr;
    float bias = (kc == 0) ? b2[e * DDIM + gcol] : 0.f;
#pragma unroll
    for (int i = 0; i < 4; i++) {
      int rl = wm + i * 16 + kg * 4;
#pragma unroll
      for (int r = 0; r < 4; r++) {
        int grow = tm * BM + rl + r;
        int tok = rtok[grow];
        if (tok >= 0) {
          float v = (acc[i][j][r] + bias) * rwgt[grow];
          atomicAdd(&out[(size_t)tok * DDIM + gcol], v);
        }
      }
    }
  }
}

extern "C" void kernel_launch(void* const* d_in, const int* in_sizes, int n_in,
                              void* d_out, int out_size, void* d_ws, size_t ws_size,
                              hipStream_t stream) {
  const float* x  = (const float*)d_in[0];
  const float* gw = (const float*)d_in[1];
  const float* gb = (const float*)d_in[2];
  const float* w1 = (const float*)d_in[3];
  const float* b1 = (const float*)d_in[4];
  const float* w2 = (const float*)d_in[5];
  const float* b2 = (const float*)d_in[6];
  float* out = (float*)d_out;
  char* ws = (char*)d_ws;

  // ws header (1 MB): fill|pbase|texp | rtok | rwgt | toke | tokw | bcnt@640K | trow@768K
  int*    fill  = (int*)(ws + 32);
  int*    pbase = (int*)(ws + 64);
  int*    texp  = (int*)(ws + 128);
  int*    rtok  = (int*)(ws + 1024);
  float*  rwgt  = (float*)(ws + 1024 + (size_t)MAXROWS * 4);
  int2*   toke  = (int2*)(ws + 1024 + (size_t)MAXROWS * 8);
  float2* tokw  = (float2*)(ws + 1024 + (size_t)MAXROWS * 8 + (size_t)T_TOK * 8);
  int*    bcnt  = (int*)(ws + 640 * 1024);
  int*    trow  = (int*)(ws + 768 * 1024);
  size_t wbytes = (size_t)NEXP * DDIM * HDIM * 2;   // 67.1 MB
  short*  w1t   = (short*)(ws + (1 << 20));
  short*  w2t   = (short*)(ws + (1 << 20) + wbytes);
  short*  xb    = (short*)(ws + (1 << 20) + 2 * wbytes);
  size_t xend   = (1 << 20) + 2 * wbytes + (size_t)T_TOK * DDIM * 2;
  size_t o2b    = (size_t)MAXROWS * DDIM * 2;       // 35.7 MB (bf16)
  size_t hbytes = (size_t)MAXTILES * BM * HDIM * 2; // 142.6 MB

  bool dense = ws_size >= xend + o2b + hbytes;

  hipMemsetAsync(ws, 0, 128, stream);
  hipMemsetAsync(rtok, 0xFF, (size_t)MAXROWS * 4, stream);

  k_front<<<NGATE + NTR1 + NTR2, 256, 0, stream>>>(x, gw, gb, w1, w2,
                                                   toke, tokw, bcnt, xb, w1t, w2t);
  k_plan<<<1, 256, 0, stream>>>(bcnt, pbase, texp);
  k_scatter<<<T_TOK / 256, 256, 0, stream>>>(toke, tokw, pbase, fill, rtok, rwgt, trow);

  if (dense) {
    short* out2b = (short*)(ws + xend);
    short* hbuf  = (short*)(ws + xend + o2b);
    k_ffn1<<<dim3(HDIM / BN, MAXTILES), 256, 0, stream>>>(xb, w1t, b1, rtok, texp,
                                                          0, hbuf);
    k_ffn2d<<<dim3(DDIM / BN, MAXTILES), 256, 0, stream>>>(hbuf, w2t, texp, 0, out2b);
    k_out<<<(T_TOK * DDIM / 4) / 256, 256, 0, stream>>>(out2b, b2, toke, tokw, trow, out);
  } else {
    short* hbuf = (short*)(ws + xend);
    size_t hcap = ws_size > xend ? ws_size - xend : 0;
    int tpc = (int)(hcap / ((size_t)BM * HDIM * 2));
    if (tpc < 1) return;
    if (tpc > MAXTILES) tpc = MAXTILES;
    hipMemsetAsync(d_out, 0, (size_t)T_TOK * DDIM * 4, stream);
    for (int base = 0; base < MAXTILES; base += tpc) {
      int nt = MAXTILES - base;
      if (nt > tpc) nt = tpc;
      k_ffn1<<<dim3(HDIM / BN, nt), 256, 0, stream>>>(xb, w1t, b1, rtok, texp, base, hbuf);
      k_ffn2a<<<dim3(DDIM / BN, KS2, nt), 256, 0, stream>>>(hbuf, w2t, b2, rtok, rwgt,
                                                            texp, base, out);
    }
  }
}

// Round 23
// 542.092 us; speedup vs baseline: 1.0323x; 1.0323x over previous
//
#include <hip/hip_runtime.h>
#include <math.h>

#define T_TOK 8192
#define DDIM  1024
#define HDIM  4096
#define NEXP  8
#define BM    128                     /* row tile */
#define BN    128                     /* col tile */
#define BK    64                      /* shorts per K-tile */
#define MAXROWS (T_TOK*2 + NEXP*BM)   /* 17408 */
#define MAXTILES (MAXROWS/BM)         /* 136 */
#define KS2   2                       /* split-K for legacy atomic ffn2 */
#define NGATE (T_TOK/8)               /* 1024 gate blocks */
#define NTR1  ((HDIM/64)*(DDIM/64)*NEXP)   /* 8192 */
#define NTR2  ((DDIM/64)*(HDIM/64)*NEXP)   /* 8192 */

typedef __attribute__((ext_vector_type(8))) short short8;
typedef __attribute__((ext_vector_type(4))) short short4v;
typedef __attribute__((ext_vector_type(4))) float f32x4;

typedef const __attribute__((address_space(1))) unsigned int* gp1_t;
typedef __attribute__((address_space(3))) unsigned int* lp3_t;

__device__ __forceinline__ void gld16(const void* g, void* l) {
  __builtin_amdgcn_global_load_lds((gp1_t)g, (lp3_t)l, 16, 0, 0);
}

__device__ __forceinline__ short f2bf(float f) {
  unsigned u = __float_as_uint(f);
  u += 0x7fffu + ((u >> 16) & 1u);   // RNE
  return (short)(u >> 16);
}

__device__ __forceinline__ float bf2f(short s) {
  return __uint_as_float(((unsigned)(unsigned short)s) << 16);
}

// A&S 7.1.25 erf approximation, |eps| <= 5e-4 (<< bf16 ulp of h); NO transcendental
__device__ __forceinline__ float erf_fast(float x) {
  float ax = fabsf(x);
  float t = 1.f + ax * (0.278393f + ax * (0.230389f + ax * (0.000972f + ax * 0.078108f)));
  float t2 = t * t;
  float r = 1.f - __builtin_amdgcn_rcpf(t2 * t2);
  return copysignf(r, x);
}

// ---- transpose body: wt[e][c][r] = bf16(w[e][r][c]), one 64x64 tile ----
__device__ __forceinline__ void tr_body(float* sl /*[64][65]*/,
    const float* __restrict__ w, short* __restrict__ wt, int R, int C, int lb) {
  int ctiles = C / 64, rtiles = R / 64;
  int e  = lb / (ctiles * rtiles);
  int rm = lb % (ctiles * rtiles);
  int r0 = (rm / ctiles) * 64;
  int c0 = (rm % ctiles) * 64;
  const float* W = w + (size_t)e * R * C;
  short* O = wt + (size_t)e * R * C;
  int t = threadIdx.x;
  int lr = t >> 4, lc4 = (t & 15) * 4;
#pragma unroll
  for (int i = 0; i < 4; i++) {
    float4 v = *(const float4*)&W[(size_t)(r0 + lr + i * 16) * C + c0 + lc4];
    sl[(lr + i * 16) * 65 + lc4 + 0] = v.x;
    sl[(lr + i * 16) * 65 + lc4 + 1] = v.y;
    sl[(lr + i * 16) * 65 + lc4 + 2] = v.z;
    sl[(lr + i * 16) * 65 + lc4 + 3] = v.w;
  }
  __syncthreads();
#pragma unroll
  for (int i = 0; i < 4; i++) {
    int oc = lr + i * 16;
    short4v s;
#pragma unroll
    for (int j = 0; j < 4; j++) s[j] = f2bf(sl[(lc4 + j) * 65 + oc]);
    *(short4v*)&O[(size_t)(c0 + oc) * R + r0 + lc4] = s;
  }
}

// ---- gate body: logits, top-2, fused xb; NO global atomics (bcnt histogram) ----
__device__ __forceinline__ void gate_body(char* smem, int bid,
    const float* __restrict__ x, const float* __restrict__ gw,
    const float* __restrict__ gb, int2* __restrict__ toke,
    float2* __restrict__ tokw, int* __restrict__ bcnt, short* __restrict__ xb) {
  float* sg = (float*)smem;                   // [e][d], 32 KB
  int* lcnt = (int*)(smem + NEXP * DDIM * 4); // 8 ints
  int t = threadIdx.x;
#pragma unroll
  for (int it = 0; it < 8; ++it) {
    int l0 = (it * 256 + t) * 4;               // linear gw index (d*8+e)
    float4 v = *(const float4*)&gw[l0];
    int d = l0 >> 3, e0 = l0 & 7;
    sg[(e0 + 0) * DDIM + d] = v.x;
    sg[(e0 + 1) * DDIM + d] = v.y;
    sg[(e0 + 2) * DDIM + d] = v.z;
    sg[(e0 + 3) * DDIM + d] = v.w;
  }
  if (t < NEXP) lcnt[t] = 0;
  __syncthreads();
  int wave = t >> 6, lane = t & 63;
  int tok0 = bid * 8 + wave * 2;
#pragma unroll
  for (int tk = 0; tk < 2; ++tk) {
    int tok = tok0 + tk;
    float p[NEXP];
#pragma unroll
    for (int e = 0; e < NEXP; e++) p[e] = 0.f;
#pragma unroll
    for (int c = 0; c < 4; c++) {
      int d = c * 256 + lane * 4;
      float4 xv = *(const float4*)&x[(size_t)tok * DDIM + d];
      short4v sv;
      sv[0] = f2bf(xv.x); sv[1] = f2bf(xv.y); sv[2] = f2bf(xv.z); sv[3] = f2bf(xv.w);
      *(short4v*)&xb[(size_t)tok * DDIM + d] = sv;
#pragma unroll
      for (int e = 0; e < NEXP; e++) {
        float4 g = *(const float4*)&sg[e * DDIM + d];
        p[e] += xv.x * g.x + xv.y * g.y + xv.z * g.z + xv.w * g.w;
      }
    }
#pragma unroll
    for (int off = 32; off; off >>= 1)
#pragma unroll
      for (int e = 0; e < NEXP; e++) p[e] += __shfl_xor(p[e], off);
    if (lane == 0) {
      float l[NEXP];
#pragma unroll
      for (int e = 0; e < NEXP; e++) l[e] = p[e] + gb[e];
      int i0 = 0;
#pragma unroll
      for (int e = 1; e < NEXP; e++) if (l[e] > l[i0]) i0 = e;   // first-max (jax tie-break)
      int i1 = (i0 == 0) ? 1 : 0;
#pragma unroll
      for (int e = 0; e < NEXP; e++) if (e != i0 && l[e] > l[i1]) i1 = e;
      float ex = expf(l[i1] - l[i0]);
      float w0 = 1.f / (1.f + ex);
      toke[tok] = make_int2(i0, i1);
      tokw[tok] = make_float2(w0, 1.f - w0);
      atomicAdd(&lcnt[i0], 1);   // LDS-scope
      atomicAdd(&lcnt[i1], 1);
    }
  }
  __syncthreads();
  if (t < NEXP) bcnt[bid * NEXP + t] = lcnt[t];
}

// ---- fused front kernel: gate blocks + w1-transpose blocks + w2-transpose blocks ----
__global__ __launch_bounds__(256) void k_front(const float* __restrict__ x,
    const float* __restrict__ gw, const float* __restrict__ gb,
    const float* __restrict__ w1, const float* __restrict__ w2,
    int2* __restrict__ toke, float2* __restrict__ tokw, int* __restrict__ bcnt,
    short* __restrict__ xb, short* __restrict__ w1t, short* __restrict__ w2t) {
  __shared__ char smem[NEXP * DDIM * 4 + 64];
  int bid = blockIdx.x;
  if (bid < NGATE) {
    gate_body(smem, bid, x, gw, gb, toke, tokw, bcnt, xb);
  } else if (bid < NGATE + NTR1) {
    tr_body((float*)smem, w1, w1t, DDIM, HDIM, bid - NGATE);
  } else {
    tr_body((float*)smem, w2, w2t, HDIM, DDIM, bid - NGATE - NTR1);
  }
}

// ---------------- routing plan (256 threads; sums bcnt) ----------------
__global__ __launch_bounds__(256) void k_plan(const int* __restrict__ bcnt,
    int* __restrict__ pbase, int* __restrict__ texp) {
  __shared__ int tot[NEXP];
  __shared__ int b[NEXP + 1];
  int t = threadIdx.x;
  if (t < NEXP) tot[t] = 0;
  __syncthreads();
  int e = t & 7, sum = 0;
  for (int i = t >> 3; i < NGATE; i += 32) sum += bcnt[i * NEXP + e];
  atomicAdd(&tot[e], sum);
  __syncthreads();
  if (t == 0) {
    b[0] = 0;
#pragma unroll
    for (int ee = 0; ee < NEXP; ee++)
      b[ee + 1] = b[ee] + ((tot[ee] + BM - 1) & ~(BM - 1));
#pragma unroll
    for (int ee = 0; ee < NEXP; ee++) pbase[ee] = b[ee];
  }
  __syncthreads();
  for (int i = t; i < MAXTILES; i += 256) {
    int r0 = i * BM, ee = -1;
#pragma unroll
    for (int k = 0; k < NEXP; k++) if (r0 >= b[k] && r0 < b[k + 1]) ee = k;
    texp[i] = ee;
  }
}

// scatter: also records tok -> (row0,row1) for the atomic-free combine
__global__ __launch_bounds__(256) void k_scatter(const int2* __restrict__ toke,
    const float2* __restrict__ tokw, const int* __restrict__ pbase,
    int* __restrict__ fill, int* __restrict__ rtok, float* __restrict__ rwgt,
    int* __restrict__ trow) {
  int tok = blockIdx.x * 256 + threadIdx.x;
  if (tok >= T_TOK) return;
  int2 te = toke[tok];
  float2 tw = tokw[tok];
  int s0 = atomicAdd(&fill[te.x], 1);
  int r0 = pbase[te.x] + s0;
  rtok[r0] = tok; rwgt[r0] = tw.x; trow[tok * 2] = r0;
  int s1 = atomicAdd(&fill[te.y], 1);
  int r1 = pbase[te.y] + s1;
  rtok[r1] = tok; rwgt[r1] = tw.y; trow[tok * 2 + 1] = r1;
}

// ---- combine: out[tok] = w0*(row0+b2[e0]) + w1*(row1+b2[e1]); bf16 out2 ----
__global__ __launch_bounds__(256) void k_out(const short* __restrict__ out2b,
    const float* __restrict__ b2, const int2* __restrict__ toke,
    const float2* __restrict__ tokw, const int* __restrict__ trow,
    float* __restrict__ out) {
  int idx = blockIdx.x * 256 + threadIdx.x;
  int tok = idx >> 8;                 // 256 float4 per 1024-dim row
  int seg = (idx & 255) * 4;
  int2 te = toke[tok];
  float2 tw = tokw[tok];
  int r0 = trow[tok * 2], r1 = trow[tok * 2 + 1];
  short4v a4 = *(const short4v*)&out2b[(size_t)r0 * DDIM + seg];
  short4v c4 = *(const short4v*)&out2b[(size_t)r1 * DDIM + seg];
  float4 p0 = *(const float4*)&b2[te.x * DDIM + seg];
  float4 p1 = *(const float4*)&b2[te.y * DDIM + seg];
  float4 o;
  o.x = tw.x * (bf2f(a4[0]) + p0.x) + tw.y * (bf2f(c4[0]) + p1.x);
  o.y = tw.x * (bf2f(a4[1]) + p0.y) + tw.y * (bf2f(c4[1]) + p1.y);
  o.z = tw.x * (bf2f(a4[2]) + p0.z) + tw.y * (bf2f(c4[2]) + p1.z);
  o.w = tw.x * (bf2f(a4[3]) + p0.w) + tw.y * (bf2f(c4[3]) + p1.w);
  *(float4*)&out[(size_t)tok * DDIM + seg] = o;
}

// ============== 128x128-tile grouped GEMM, 4 waves (2M x 2N, 64x64/wave) ==========
// Round-13/16 proven config: 4 blocks/CU, XOR-8 swizzle (0 conflicts).

#define STG(ko) { \
  gld16(sA[0] + (ko), &AL[(0 * 32 + wid * 8) * BK]); \
  gld16(sA[1] + (ko), &AL[(1 * 32 + wid * 8) * BK]); \
  gld16(sA[2] + (ko), &AL[(2 * 32 + wid * 8) * BK]); \
  gld16(sA[3] + (ko), &AL[(3 * 32 + wid * 8) * BK]); \
  gld16(sB[0] + (ko), &BL[(0 * 32 + wid * 8) * BK]); \
  gld16(sB[1] + (ko), &BL[(1 * 32 + wid * 8) * BK]); \
  gld16(sB[2] + (ko), &BL[(2 * 32 + wid * 8) * BK]); \
  gld16(sB[3] + (ko), &BL[(3 * 32 + wid * 8) * BK]); }

#define MFMA_TILE { \
  __builtin_amdgcn_s_setprio(1); \
  _Pragma("unroll") \
  for (int s = 0; s < 2; ++s) { \
    int xo = ((s * 4 + kg) ^ x7) << 3; \
    short8 af[4], bg[4]; \
    _Pragma("unroll") \
    for (int i = 0; i < 4; i++) af[i] = *(short8*)&AL[(wm + i * 16 + lr) * BK + xo]; \
    _Pragma("unroll") \
    for (int j = 0; j < 4; j++) bg[j] = *(short8*)&BL[(wn + j * 16 + lr) * BK + xo]; \
    _Pragma("unroll") \
    for (int i = 0; i < 4; i++) \
    _Pragma("unroll") \
    for (int j = 0; j < 4; j++) \
      acc[i][j] = __builtin_amdgcn_mfma_f32_16x16x32_bf16(af[i], bg[j], acc[i][j], 0, 0, 0); \
  } \
  __builtin_amdgcn_s_setprio(0); }

#define GEMM_LOOP(NKv) \
  _Pragma("unroll 4") \
  for (int kt = 0; kt < (NKv); ++kt) { \
    STG(kt * BK); \
    asm volatile("s_waitcnt vmcnt(0)" ::: "memory"); \
    __syncthreads(); \
    MFMA_TILE; \
    __syncthreads(); \
  }

// ---------------- stage 1: h = gelu(x @ w1[e] + b1[e]) ----------------
__global__ __launch_bounds__(256, 4) void k_ffn1(const short* __restrict__ xb,
    const short* __restrict__ w1t, const float* __restrict__ b1,
    const int* __restrict__ rtok, const int* __restrict__ texp,
    int tile_base, short* __restrict__ hbuf) {
  int tl = blockIdx.y;
  int tm = tile_base + tl;
  int e = texp[tm];
  if (e < 0) return;
  int n0 = blockIdx.x * BN;
  const short* W = w1t + (size_t)e * HDIM * DDIM;
  __shared__ short LDSBUF[2 * BM * BK];
  short* AL = LDSBUF;
  short* BL = LDSBUF + BM * BK;
  int t = threadIdx.x, wid = t >> 6, lane = t & 63;
  int sr8 = lane >> 3, slot = lane & 7;
  int swz = (slot ^ sr8) * 8;
  const short* sA[4]; const short* sB[4];
#pragma unroll
  for (int i = 0; i < 4; i++) {
    int r = i * 32 + wid * 8 + sr8;
    int tok = rtok[tm * BM + r]; if (tok < 0) tok = 0;
    sA[i] = xb + (size_t)tok * DDIM + swz;
    sB[i] = W + (size_t)(n0 + r) * DDIM + swz;
  }

  f32x4 acc[4][4];
#pragma unroll
  for (int i = 0; i < 4; i++)
#pragma unroll
    for (int j = 0; j < 4; j++) acc[i][j] = (f32x4){0.f, 0.f, 0.f, 0.f};

  int wm = (wid >> 1) * 64, wn = (wid & 1) * 64;
  int lr = lane & 15, kg = lane >> 4, x7 = lr & 7;

  GEMM_LOOP(DDIM / BK)   // 16

  // LDS-staged vectorized epilogue (wave-private [32][68] region, no barriers)
  short* SB = LDSBUF + wid * (32 * 68);
#pragma unroll
  for (int p = 0; p < 2; ++p) {
#pragma unroll
    for (int i2 = 0; i2 < 2; ++i2) {
      int i = p * 2 + i2;
#pragma unroll
      for (int j = 0; j < 4; ++j) {
        int col = j * 16 + lr;
        float bias = b1[e * HDIM + n0 + wn + col];
#pragma unroll
        for (int r = 0; r < 4; ++r) {
          float v = acc[i][j][r] + bias;
          v = 0.5f * v * (1.f + erf_fast(v * 0.70710678118f));
          SB[(i2 * 16 + kg * 4 + r) * 68 + col] = f2bf(v);
        }
      }
    }
    int lrow = lane >> 1, c0 = (lane & 1) * 32;
    size_t grow = (size_t)(tl * BM + wm + p * 32 + lrow);
#pragma unroll
    for (int s = 0; s < 4; ++s) {
      short8 v = *(short8*)&SB[lrow * 68 + c0 + s * 8];
      *(short8*)&hbuf[grow * HDIM + n0 + wn + c0 + s * 8] = v;
    }
  }
}

// ------- stage 2 (dense): out2b[row] = bf16(h @ w2[e]); XCD-colocated supertile -------
// flat id -> supertile of 8 tm x 8 n0 with tm = wi&7 (FAST axis): the 8 blocks
// sharing an hbuf panel sit at ids {wi, wi+8, ..} === same (mod 8) -> same XCD L2
// (round-robin dispatch) -> panel L2-filled ~once instead of 8x. w2t sharers are
// 8 consecutive ids: 8 XCDs but temporally adjacent -> MALL-hot fills.
__global__ __launch_bounds__(256, 4) void k_ffn2d(const short* __restrict__ hbuf,
    const short* __restrict__ w2t, const int* __restrict__ texp,
    int tile_base, short* __restrict__ out2b) {
  int flat = blockIdx.y * gridDim.x + blockIdx.x;
  int st = flat >> 6, wi = flat & 63;
  int tm = tile_base + st * 8 + (wi & 7);
  int n0 = (wi >> 3) * BN;
  int e = texp[tm];
  if (e < 0) return;
  const short* W = w2t + (size_t)e * DDIM * HDIM;
  __shared__ short LDSBUF[2 * BM * BK];
  short* AL = LDSBUF;
  short* BL = LDSBUF + BM * BK;
  int t = threadIdx.x, wid = t >> 6, lane = t & 63;
  int sr8 = lane >> 3, slot = lane & 7;
  int swz = (slot ^ sr8) * 8;
  const short* sA[4]; const short* sB[4];
#pragma unroll
  for (int i = 0; i < 4; i++) {
    int r = i * 32 + wid * 8 + sr8;
    sA[i] = hbuf + (size_t)(tm * BM + r) * HDIM + swz;
    sB[i] = W + (size_t)(n0 + r) * HDIM + swz;
  }

  f32x4 acc[4][4];
#pragma unroll
  for (int i = 0; i < 4; i++)
#pragma unroll
    for (int j = 0; j < 4; j++) acc[i][j] = (f32x4){0.f, 0.f, 0.f, 0.f};

  int wm = (wid >> 1) * 64, wn = (wid & 1) * 64;
  int lr = lane & 15, kg = lane >> 4, x7 = lr & 7;

  GEMM_LOOP(HDIM / BK)   // 64

  // bf16 epilogue: wave-private [16][68]-short LDS staging, short8 stores
  short* SB = LDSBUF + wid * (16 * 68);
#pragma unroll
  for (int i = 0; i < 4; ++i) {
#pragma unroll
    for (int j = 0; j < 4; ++j)
#pragma unroll
      for (int r = 0; r < 4; ++r)
        SB[(kg * 4 + r) * 68 + j * 16 + lr] = f2bf(acc[i][j][r]);
    int lrow = lane >> 2, c0 = (lane & 3) * 16;
    size_t grow = (size_t)(tm * BM + wm + i * 16 + lrow);
#pragma unroll
    for (int s = 0; s < 2; ++s) {
      short8 v = *(short8*)&SB[lrow * 68 + c0 + s * 8];
      *(short8*)&out2b[grow * DDIM + n0 + wn + c0 + s * 8] = v;
    }
  }
}

// ------- stage 2 (legacy atomic, split-K): fallback when ws is small -------
__global__ __launch_bounds__(256, 4) void k_ffn2a(const short* __restrict__ hbuf,
    const short* __restrict__ w2t, const float* __restrict__ b2,
    const int* __restrict__ rtok, const float* __restrict__ rwgt,
    const int* __restrict__ texp, int tile_base, float* __restrict__ out) {
  int tl = blockIdx.z;
  int tm = tile_base + tl;
  int e = texp[tm];
  if (e < 0) return;
  int kc = blockIdx.y;
  int n0 = blockIdx.x * BN;
  const short* W = w2t + (size_t)e * DDIM * HDIM;
  __shared__ short LDSBUF[2 * BM * BK];
  short* AL = LDSBUF;
  short* BL = LDSBUF + BM * BK;
  int t = threadIdx.x, wid = t >> 6, lane = t & 63;
  int sr8 = lane >> 3, slot = lane & 7;
  int swz = (slot ^ sr8) * 8;
  const int NK = HDIM / BK / KS2;
  int kbase = kc * NK * BK;
  const short* sA[4]; const short* sB[4];
#pragma unroll
  for (int i = 0; i < 4; i++) {
    int r = i * 32 + wid * 8 + sr8;
    sA[i] = hbuf + (size_t)(tl * BM + r) * HDIM + kbase + swz;
    sB[i] = W + (size_t)(n0 + r) * HDIM + kbase + swz;
  }
  f32x4 acc[4][4];
#pragma unroll
  for (int i = 0; i < 4; i++)
#pragma unroll
    for (int j = 0; j < 4; j++) acc[i][j] = (f32x4){0.f, 0.f, 0.f, 0.f};
  int wm = (wid >> 1) * 64, wn = (wid & 1) * 64;
  int lr = lane & 15, kg = lane >> 4, x7 = lr & 7;

  GEMM_LOOP(NK)

#pragma unroll
  for (int j = 0; j < 4; j++) {
    int gcol = n0 + wn + j * 16 + lr;
    float bias = (kc == 0) ? b2[e * DDIM + gcol] : 0.f;
#pragma unroll
    for (int i = 0; i < 4; i++) {
      int rl = wm + i * 16 + kg * 4;
#pragma unroll
      for (int r = 0; r < 4; r++) {
        int grow = tm * BM + rl + r;
        int tok = rtok[grow];
        if (tok >= 0) {
          float v = (acc[i][j][r] + bias) * rwgt[grow];
          atomicAdd(&out[(size_t)tok * DDIM + gcol], v);
        }
      }
    }
  }
}

extern "C" void kernel_launch(void* const* d_in, const int* in_sizes, int n_in,
                              void* d_out, int out_size, void* d_ws, size_t ws_size,
                              hipStream_t stream) {
  const float* x  = (const float*)d_in[0];
  const float* gw = (const float*)d_in[1];
  const float* gb = (const float*)d_in[2];
  const float* w1 = (const float*)d_in[3];
  const float* b1 = (const float*)d_in[4];
  const float* w2 = (const float*)d_in[5];
  const float* b2 = (const float*)d_in[6];
  float* out = (float*)d_out;
  char* ws = (char*)d_ws;

  // ws header (1 MB): fill|pbase|texp | rtok | rwgt | toke | tokw | bcnt@640K | trow@768K
  int*    fill  = (int*)(ws + 32);
  int*    pbase = (int*)(ws + 64);
  int*    texp  = (int*)(ws + 128);
  int*    rtok  = (int*)(ws + 1024);
  float*  rwgt  = (float*)(ws + 1024 + (size_t)MAXROWS * 4);
  int2*   toke  = (int2*)(ws + 1024 + (size_t)MAXROWS * 8);
  float2* tokw  = (float2*)(ws + 1024 + (size_t)MAXROWS * 8 + (size_t)T_TOK * 8);
  int*    bcnt  = (int*)(ws + 640 * 1024);
  int*    trow  = (int*)(ws + 768 * 1024);
  size_t wbytes = (size_t)NEXP * DDIM * HDIM * 2;   // 67.1 MB
  short*  w1t   = (short*)(ws + (1 << 20));
  short*  w2t   = (short*)(ws + (1 << 20) + wbytes);
  short*  xb    = (short*)(ws + (1 << 20) + 2 * wbytes);
  size_t xend   = (1 << 20) + 2 * wbytes + (size_t)T_TOK * DDIM * 2;
  size_t o2b    = (size_t)MAXROWS * DDIM * 2;       // 35.7 MB (bf16)
  size_t hbytes = (size_t)MAXTILES * BM * HDIM * 2; // 142.6 MB

  bool dense = ws_size >= xend + o2b + hbytes;

  hipMemsetAsync(ws, 0, 128, stream);
  hipMemsetAsync(rtok, 0xFF, (size_t)MAXROWS * 4, stream);

  k_front<<<NGATE + NTR1 + NTR2, 256, 0, stream>>>(x, gw, gb, w1, w2,
                                                   toke, tokw, bcnt, xb, w1t, w2t);
  k_plan<<<1, 256, 0, stream>>>(bcnt, pbase, texp);
  k_scatter<<<T_TOK / 256, 256, 0, stream>>>(toke, tokw, pbase, fill, rtok, rwgt, trow);

  if (dense) {
    short* out2b = (short*)(ws + xend);
    short* hbuf  = (short*)(ws + xend + o2b);
    k_ffn1<<<dim3(HDIM / BN, MAXTILES), 256, 0, stream>>>(xb, w1t, b1, rtok, texp,
                                                          0, hbuf);
    k_ffn2d<<<dim3(DDIM / BN, MAXTILES), 256, 0, stream>>>(hbuf, w2t, texp, 0, out2b);
    k_out<<<(T_TOK * DDIM / 4) / 256, 256, 0, stream>>>(out2b, b2, toke, tokw, trow, out);
  } else {
    short* hbuf = (short*)(ws + xend);
    size_t hcap = ws_size > xend ? ws_size - xend : 0;
    int tpc = (int)(hcap / ((size_t)BM * HDIM * 2));
    if (tpc < 1) return;
    if (tpc > MAXTILES) tpc = MAXTILES;
    hipMemsetAsync(d_out, 0, (size_t)T_TOK * DDIM * 4, stream);
    for (int base = 0; base < MAXTILES; base += tpc) {
      int nt = MAXTILES - base;
      if (nt > tpc) nt = tpc;
      k_ffn1<<<dim3(HDIM / BN, nt), 256, 0, stream>>>(xb, w1t, b1, rtok, texp, base, hbuf);
      k_ffn2a<<<dim3(DDIM / BN, KS2, nt), 256, 0, stream>>>(hbuf, w2t, b2, rtok, rwgt,
                                                            texp, base, out);
    }
  }
}